// Round 1
// baseline (10699.685 us; speedup 1.0000x reference)
//
#include <hip/hip_runtime.h>
#include <math.h>

#define BB 32
#define EE 512
#define VV 8192
#define TT 16
#define LL 4
#define FFD 2048
#define NHD 8
#define HDD 64
#define SCALE_EMB 22.627416997969522f

// ---------------- helpers ----------------
__device__ __forceinline__ float wave_sum(float v){
  for (int o = 32; o; o >>= 1) v += __shfl_down(v, o);
  return __shfl(v, 0);
}
__device__ __forceinline__ float wave_max(float v){
  for (int o = 32; o; o >>= 1) v = fmaxf(v, __shfl_down(v, o));
  return __shfl(v, 0);
}
__device__ __forceinline__ unsigned short f_to_bf(float f){
  unsigned u = __float_as_uint(f);
  unsigned r = (u + 0x7fffu + ((u >> 16) & 1u)) >> 16;
  return (unsigned short)r;
}
__device__ __forceinline__ float2 bf2_to_f2(const unsigned short* p){
  unsigned u = *(const unsigned*)p;
  float2 r;
  r.x = __uint_as_float(u << 16);
  r.y = __uint_as_float(u & 0xffff0000u);
  return r;
}

// Load [B,E] input into LDS as bf16, with optional LayerNorm applied (prev layer ln3).
__device__ __forceinline__ void load_x_ln(unsigned short* xs,
    const float* __restrict__ xraw, const float* __restrict__ ybuf,
    const float* __restrict__ g, const float* __restrict__ bt, int use_ln){
  if (!use_ln){
    for (int i = threadIdx.x; i < BB*EE; i += blockDim.x) xs[i] = f_to_bf(xraw[i]);
  } else {
    const int lane = threadIdx.x & 63, wv = threadIdx.x >> 6;
    for (int r = wv*8; r < wv*8 + 8; ++r){
      float vals[8]; float s = 0.f, s2 = 0.f;
      #pragma unroll
      for (int j = 0; j < 8; ++j){
        float v = ybuf[r*EE + lane + j*64];
        vals[j] = v; s += v; s2 += v*v;
      }
      s = wave_sum(s); s2 = wave_sum(s2);
      float m = s * (1.f/EE);
      float inv = rsqrtf(s2*(1.f/EE) - m*m + 1e-5f);
      #pragma unroll
      for (int j = 0; j < 8; ++j){
        int c = lane + j*64;
        xs[r*EE + c] = f_to_bf((vals[j]-m)*inv*g[c] + bt[c]);
      }
    }
  }
  __syncthreads();
}

// GEMM core: out[f0+0..63][b=0..31] += sum_{k=0..511} w[f][k] * x[b][k]
// w fp32 global row-major (ld=ldw), x bf16 in LDS [32][512]. wt = LDS scratch [64k][68].
// thread: fg=t&15 -> 4 f's (fg*4+i), bg=t>>4 -> 2 b's (bg*2+j). acc[4][2] caller-init.
__device__ __forceinline__ void gemm_chunk(const float* __restrict__ wrow0, int ldw,
    const unsigned short* xs, float* wt, float acc[4][2]){
  const int t = threadIdx.x, fg = t & 15, bg = t >> 4;
  #pragma unroll 1
  for (int c = 0; c < 8; ++c){
    const int k0 = c*64;
    __syncthreads();
    {
      int i = t*4;
      #pragma unroll
      for (int p = 0; p < 4; ++p, i += 1024){
        const int fr = i >> 6, kk = i & 63;
        float4 v = *(const float4*)(wrow0 + (size_t)fr*ldw + k0 + kk);
        wt[(kk+0)*68 + fr] = v.x;
        wt[(kk+1)*68 + fr] = v.y;
        wt[(kk+2)*68 + fr] = v.z;
        wt[(kk+3)*68 + fr] = v.w;
      }
    }
    __syncthreads();
    const unsigned short* xr0 = xs + (bg*2)*EE + k0;
    const unsigned short* xr1 = xr0 + EE;
    #pragma unroll 8
    for (int k = 0; k < 64; k += 2){
      float w0[4], w1[4];
      *(float4*)w0 = *(const float4*)(wt + (k+0)*68 + fg*4);
      *(float4*)w1 = *(const float4*)(wt + (k+1)*68 + fg*4);
      float2 xv0 = bf2_to_f2(xr0 + k);
      float2 xv1 = bf2_to_f2(xr1 + k);
      #pragma unroll
      for (int i = 0; i < 4; ++i){
        acc[i][0] += w0[i]*xv0.x + w1[i]*xv0.y;
        acc[i][1] += w0[i]*xv1.x + w1[i]*xv1.y;
      }
    }
  }
}

// ---------------- kernels ----------------

// eos row of sequence output + initial x = special_symbol broadcast
__global__ __launch_bounds__(256) void k_init(const float* __restrict__ special,
    float* __restrict__ dseq, float* __restrict__ x){
  int idx = blockIdx.x*256 + threadIdx.x;
  if (idx < BB*VV){
    int b = idx >> 13, v = idx & (VV-1);
    dseq[(size_t)b*((TT+1)*VV) + (size_t)TT*VV + v] = (v == 0) ? 1.f : 0.f;
  } else {
    int i = idx - BB*VV;  // grid sized exactly: BB*VV + BB*EE
    x[i] = special[i & (EE-1)];
  }
}

// venc[l][b][e] = enc[b] @ ca_wv[l].T + ca_bv[l]   (cross-attn V of the single encoder pos)
__global__ __launch_bounds__(256) void k_penc(const float* __restrict__ enc,
    const float* __restrict__ w, const float* __restrict__ bias, float* __restrict__ venc){
  __shared__ unsigned short xs[BB*EE];
  __shared__ float wt[64*68];
  const int l = blockIdx.x >> 3, et = blockIdx.x & 7;
  for (int i = threadIdx.x; i < BB*EE; i += 256) xs[i] = f_to_bf(enc[i]);
  const int t = threadIdx.x, fg = t & 15, bg = t >> 4;
  const int f0 = et*64;
  const float* wl = w + (size_t)l*3*EE*EE + (size_t)(2*EE + f0)*EE;
  const float* bl = bias + l*3*EE + 2*EE + f0;
  float acc[4][2];
  #pragma unroll
  for (int i = 0; i < 4; ++i){ float bv = bl[fg*4+i]; acc[i][0] = bv; acc[i][1] = bv; }
  gemm_chunk(wl, EE, xs, wt, acc);
  #pragma unroll
  for (int i = 0; i < 4; ++i)
    #pragma unroll
    for (int j = 0; j < 2; ++j)
      venc[(size_t)l*BB*EE + (bg*2+j)*EE + f0 + fg*4 + i] = acc[i][j];
}

// cac[l][b][e] = venc[l][b] @ ca_out_w[l].T + ca_out_b[l]   (constant cross-attn output)
__global__ __launch_bounds__(256) void k_pca(const float* __restrict__ venc,
    const float* __restrict__ w, const float* __restrict__ bias, float* __restrict__ cac){
  __shared__ unsigned short xs[BB*EE];
  __shared__ float wt[64*68];
  const int l = blockIdx.x >> 3, et = blockIdx.x & 7;
  const float* vin = venc + (size_t)l*BB*EE;
  for (int i = threadIdx.x; i < BB*EE; i += 256) xs[i] = f_to_bf(vin[i]);
  const int t = threadIdx.x, fg = t & 15, bg = t >> 4;
  const int f0 = et*64;
  const float* wl = w + (size_t)l*EE*EE + (size_t)f0*EE;
  const float* bl = bias + l*EE + f0;
  float acc[4][2];
  #pragma unroll
  for (int i = 0; i < 4; ++i){ float bv = bl[fg*4+i]; acc[i][0] = bv; acc[i][1] = bv; }
  gemm_chunk(wl, EE, xs, wt, acc);
  #pragma unroll
  for (int i = 0; i < 4; ++i)
    #pragma unroll
    for (int j = 0; j < 2; ++j)
      cac[(size_t)l*BB*EE + (bg*2+j)*EE + f0 + fg*4 + i] = acc[i][j];
}

// qkv projection for the new position; q -> qbuf, k/v -> caches at tpos
__global__ __launch_bounds__(256) void k_qkv(
    const float* __restrict__ xraw, const float* __restrict__ ybuf,
    const float* __restrict__ lng, const float* __restrict__ lnb, int use_ln,
    const float* __restrict__ w, const float* __restrict__ bias,
    float* __restrict__ qbuf, float* __restrict__ kc, float* __restrict__ vc, int tpos){
  __shared__ unsigned short xs[BB*EE];
  __shared__ float wt[64*68];
  load_x_ln(xs, xraw, ybuf, lng, lnb, use_ln);
  const int t = threadIdx.x, fg = t & 15, bg = t >> 4;
  const int f0 = blockIdx.x*64;
  float acc[4][2];
  #pragma unroll
  for (int i = 0; i < 4; ++i){ float bv = bias[f0+fg*4+i]; acc[i][0] = bv; acc[i][1] = bv; }
  gemm_chunk(w + (size_t)f0*EE, EE, xs, wt, acc);
  #pragma unroll
  for (int i = 0; i < 4; ++i)
    #pragma unroll
    for (int j = 0; j < 2; ++j){
      int f = f0 + fg*4 + i, b = bg*2 + j;
      float v = acc[i][j];
      if (f < EE){
        qbuf[b*EE + f] = v;
      } else if (f < 2*EE){
        int ff = f - EE, h = ff >> 6, d = ff & 63;
        kc[((size_t)(b*NHD + h)*TT + tpos)*HDD + d] = v;
      } else {
        int ff = f - 2*EE, h = ff >> 6, d = ff & 63;
        vc[((size_t)(b*NHD + h)*TT + tpos)*HDD + d] = v;
      }
    }
}

// per-row: attention over cache + out-proj + residual + LN1 + ca_const + LN2 -> xout
// also writes ybuf = xout + b2 (pre-init for ffn2's atomic k-split accumulation)
__global__ __launch_bounds__(256) void k_attnfused(
    const float* __restrict__ xraw, const float* __restrict__ ybuf_in,
    const float* __restrict__ lng, const float* __restrict__ lnb, int use_ln,
    const float* __restrict__ qbuf, const float* __restrict__ kc, const float* __restrict__ vc, int tlen,
    const float* __restrict__ ow, const float* __restrict__ ob,
    const float* __restrict__ l1g, const float* __restrict__ l1b,
    const float* __restrict__ l2g, const float* __restrict__ l2b,
    const float* __restrict__ cac, const float* __restrict__ b2l,
    float* __restrict__ xout, float* __restrict__ ybuf_out){
  const int b = blockIdx.x, t = threadIdx.x, lane = t & 63, wv = t >> 6;
  __shared__ float xrow[EE];
  __shared__ float orow[EE];
  __shared__ float att[NHD*16];
  __shared__ float red[8];
  if (!use_ln){
    for (int i = t; i < EE; i += 256) xrow[i] = xraw[b*EE + i];
  } else if (wv == 0){
    float vals[8]; float s = 0.f, s2 = 0.f;
    #pragma unroll
    for (int j = 0; j < 8; ++j){
      float v = ybuf_in[b*EE + lane + j*64];
      vals[j] = v; s += v; s2 += v*v;
    }
    s = wave_sum(s); s2 = wave_sum(s2);
    float m = s*(1.f/EE), inv = rsqrtf(s2*(1.f/EE) - m*m + 1e-5f);
    #pragma unroll
    for (int j = 0; j < 8; ++j){
      int c = lane + j*64;
      xrow[c] = (vals[j]-m)*inv*lng[c] + lnb[c];
    }
  }
  __syncthreads();
  // attention: wave wv handles heads 2wv, 2wv+1
  #pragma unroll
  for (int hh = 0; hh < 2; ++hh){
    const int h = wv*2 + hh;
    const float* kh = kc + (size_t)(b*NHD + h)*TT*HDD;
    const float* vh = vc + (size_t)(b*NHD + h)*TT*HDD;
    const float* qh = qbuf + b*EE + h*HDD;
    float sc = -1e30f;
    if (lane < tlen){
      float a = 0.f;
      for (int d = 0; d < HDD; d += 4){
        float4 qv = *(const float4*)(qh + d);
        float4 kv = *(const float4*)(kh + lane*HDD + d);
        a += qv.x*kv.x + qv.y*kv.y + qv.z*kv.z + qv.w*kv.w;
      }
      sc = a*0.125f;  // 1/sqrt(64)
    }
    float m = wave_max(sc);
    float e = (lane < tlen) ? __expf(sc - m) : 0.f;
    float s = wave_sum(e);
    if (lane < 16) att[h*16 + lane] = e / s;
    float o = 0.f;
    for (int j = 0; j < tlen; ++j) o += att[h*16 + j] * vh[j*HDD + lane];
    orow[h*HDD + lane] = o;
  }
  __syncthreads();
  // out-projection + residual
  float y1[2];
  #pragma unroll
  for (int i = 0; i < 2; ++i){
    const int f = t + i*256;
    const float* wr = ow + (size_t)f*EE;
    float a = ob[f];
    for (int k = 0; k < EE; k += 4){
      float4 w4 = *(const float4*)(wr + k);
      a += w4.x*orow[k] + w4.y*orow[k+1] + w4.z*orow[k+2] + w4.w*orow[k+3];
    }
    y1[i] = xrow[f] + a;
  }
  // LN1
  float s = y1[0]+y1[1], s2 = y1[0]*y1[0] + y1[1]*y1[1];
  for (int o = 32; o; o >>= 1){ s += __shfl_down(s, o); s2 += __shfl_down(s2, o); }
  if (lane == 0){ red[wv] = s; red[4+wv] = s2; }
  __syncthreads();
  float ts = red[0]+red[1]+red[2]+red[3], ts2 = red[4]+red[5]+red[6]+red[7];
  float mean = ts*(1.f/EE), inv = rsqrtf(ts2*(1.f/EE) - mean*mean + 1e-5f);
  float y2[2];
  #pragma unroll
  for (int i = 0; i < 2; ++i){
    int f = t + i*256;
    y2[i] = (y1[i]-mean)*inv*l1g[f] + l1b[f] + cac[b*EE + f];
  }
  __syncthreads();
  // LN2
  s = y2[0]+y2[1]; s2 = y2[0]*y2[0] + y2[1]*y2[1];
  for (int o = 32; o; o >>= 1){ s += __shfl_down(s, o); s2 += __shfl_down(s2, o); }
  if (lane == 0){ red[wv] = s; red[4+wv] = s2; }
  __syncthreads();
  ts = red[0]+red[1]+red[2]+red[3]; ts2 = red[4]+red[5]+red[6]+red[7];
  mean = ts*(1.f/EE); inv = rsqrtf(ts2*(1.f/EE) - mean*mean + 1e-5f);
  #pragma unroll
  for (int i = 0; i < 2; ++i){
    int f = t + i*256;
    float xv = (y2[i]-mean)*inv*l2g[f] + l2b[f];
    xout[b*EE + f] = xv;
    ybuf_out[b*EE + f] = xv + b2l[f];  // pre-init for ffn2 atomics (residual + bias)
  }
}

// H = gelu(x @ w1.T + b1)
__global__ __launch_bounds__(256) void k_ffn1(const float* __restrict__ x,
    const float* __restrict__ w, const float* __restrict__ bias, float* __restrict__ H){
  __shared__ unsigned short xs[BB*EE];
  __shared__ float wt[64*68];
  load_x_ln(xs, x, nullptr, nullptr, nullptr, 0);
  const int t = threadIdx.x, fg = t & 15, bg = t >> 4;
  const int f0 = blockIdx.x*64;
  float acc[4][2];
  #pragma unroll
  for (int i = 0; i < 4; ++i){ float bv = bias[f0+fg*4+i]; acc[i][0] = bv; acc[i][1] = bv; }
  gemm_chunk(w + (size_t)f0*EE, EE, xs, wt, acc);
  #pragma unroll
  for (int i = 0; i < 4; ++i)
    #pragma unroll
    for (int j = 0; j < 2; ++j){
      float v = acc[i][j];
      v = 0.5f*v*(1.f + erff(v*0.70710678118654752f));
      H[(bg*2+j)*FFD + f0 + fg*4 + i] = v;
    }
}

// y += H_chunk @ w2_chunk.T  (k-split over 4 chunks of 512; y pre-init'd by k_attnfused)
__global__ __launch_bounds__(256) void k_ffn2(const float* __restrict__ H,
    const float* __restrict__ w, float* __restrict__ ybuf){
  __shared__ unsigned short xs[BB*EE];
  __shared__ float wt[64*68];
  const int f0 = (blockIdx.x & 7)*64, c = blockIdx.x >> 3;
  for (int i = threadIdx.x; i < BB*EE; i += 256){
    int b = i >> 9, kk = i & 511;
    xs[i] = f_to_bf(H[b*FFD + c*512 + kk]);
  }
  const int t = threadIdx.x, fg = t & 15, bg = t >> 4;
  float acc[4][2] = {{0.f,0.f},{0.f,0.f},{0.f,0.f},{0.f,0.f}};
  gemm_chunk(w + (size_t)f0*FFD + c*512, FFD, xs, wt, acc);
  #pragma unroll
  for (int i = 0; i < 4; ++i)
    #pragma unroll
    for (int j = 0; j < 2; ++j)
      atomicAdd(&ybuf[(bg*2+j)*EE + f0 + fg*4 + i], acc[i][j]);
}

// logits = LN3(y) @ out_w.T + out_b
__global__ __launch_bounds__(256) void k_logits(const float* __restrict__ ybuf,
    const float* __restrict__ lng, const float* __restrict__ lnb,
    const float* __restrict__ w, const float* __restrict__ bias, float* __restrict__ logits){
  __shared__ unsigned short xs[BB*EE];
  __shared__ float wt[64*68];
  load_x_ln(xs, nullptr, ybuf, lng, lnb, 1);
  const int t = threadIdx.x, fg = t & 15, bg = t >> 4;
  const int f0 = blockIdx.x*64;
  float acc[4][2];
  #pragma unroll
  for (int i = 0; i < 4; ++i){ float bv = bias[f0+fg*4+i]; acc[i][0] = bv; acc[i][1] = bv; }
  gemm_chunk(w + (size_t)f0*EE, EE, xs, wt, acc);
  #pragma unroll
  for (int i = 0; i < 4; ++i)
    #pragma unroll
    for (int j = 0; j < 2; ++j)
      logits[(bg*2+j)*VV + f0 + fg*4 + i] = acc[i][j];
}

// distrib = softmax(logits) -> d_out distribs; sample = softmax(logits+gumbel) -> d_out sequence
// also zeros x for the upcoming embedding accumulation
__global__ __launch_bounds__(256) void k_softmax(const float* __restrict__ logits,
    const float* __restrict__ gum, float* __restrict__ dseq, float* __restrict__ ddist,
    float* __restrict__ x, int step){
  const int b = blockIdx.x, t = threadIdx.x, lane = t & 63, wv = t >> 6;
  __shared__ float red[8];
  const float* lr = logits + (size_t)b*VV;
  const float* gr = gum + (size_t)b*VV;
  float m1 = -1e30f, m2 = -1e30f;
  for (int i = t; i < VV; i += 256){
    float l = lr[i];
    m1 = fmaxf(m1, l);
    m2 = fmaxf(m2, l + gr[i]);
  }
  for (int o = 32; o; o >>= 1){ m1 = fmaxf(m1, __shfl_down(m1,o)); m2 = fmaxf(m2, __shfl_down(m2,o)); }
  if (lane == 0){ red[wv] = m1; red[4+wv] = m2; }
  __syncthreads();
  m1 = fmaxf(fmaxf(red[0],red[1]), fmaxf(red[2],red[3]));
  m2 = fmaxf(fmaxf(red[4],red[5]), fmaxf(red[6],red[7]));
  __syncthreads();
  float s1 = 0.f, s2 = 0.f;
  for (int i = t; i < VV; i += 256){
    float l = lr[i];
    s1 += __expf(l - m1);
    s2 += __expf(l + gr[i] - m2);
  }
  for (int o = 32; o; o >>= 1){ s1 += __shfl_down(s1,o); s2 += __shfl_down(s2,o); }
  if (lane == 0){ red[wv] = s1; red[4+wv] = s2; }
  __syncthreads();
  s1 = red[0]+red[1]+red[2]+red[3];
  s2 = red[4]+red[5]+red[6]+red[7];
  float r1 = 1.f/s1, r2 = 1.f/s2;
  float* dq = dseq + (size_t)b*((TT+1)*VV) + (size_t)step*VV;
  float* dd = ddist + (size_t)b*VV;
  for (int i = t; i < VV; i += 256){
    float l = lr[i];
    dd[i] = __expf(l - m1)*r1;
    dq[i] = __expf(l + gr[i] - m2)*r2;
  }
  for (int i = t; i < EE; i += 256) x[b*EE + i] = 0.f;
}

// x += (sample @ embed_weight) * sqrt(E); k-split over 16 chunks, atomic accumulate
__global__ __launch_bounds__(256) void k_embed(const float* __restrict__ emb,
    const float* __restrict__ dseq, int step, float* __restrict__ x){
  const int et = blockIdx.x & 7, kc = blockIdx.x >> 3;  // 8 e-tiles x 16 k-chunks
  const int t = threadIdx.x, eg = t & 15, bh = t >> 4;
  const int e0 = et*64, k0 = kc*512;
  float acc[4][2] = {{0.f,0.f},{0.f,0.f},{0.f,0.f},{0.f,0.f}};
  const float* s0 = dseq + (size_t)(bh*2)*((TT+1)*VV) + (size_t)step*VV + k0;
  const float* s1 = s0 + (size_t)(TT+1)*VV;
  const float* ebase = emb + (size_t)k0*EE + e0 + eg*4;
  for (int k = 0; k < 512; k += 4){
    float sv0[4], sv1[4];
    *(float4*)sv0 = *(const float4*)(s0 + k);
    *(float4*)sv1 = *(const float4*)(s1 + k);
    #pragma unroll
    for (int kk = 0; kk < 4; ++kk){
      float ev[4];
      *(float4*)ev = *(const float4*)(ebase + (size_t)(k+kk)*EE);
      #pragma unroll
      for (int i = 0; i < 4; ++i){
        acc[i][0] += ev[i]*sv0[kk];
        acc[i][1] += ev[i]*sv1[kk];
      }
    }
  }
  #pragma unroll
  for (int i = 0; i < 4; ++i){
    atomicAdd(&x[(bh*2+0)*EE + e0 + eg*4 + i], acc[i][0]*SCALE_EMB);
    atomicAdd(&x[(bh*2+1)*EE + e0 + eg*4 + i], acc[i][1]*SCALE_EMB);
  }
}

// ---------------- host ----------------
extern "C" void kernel_launch(void* const* d_in, const int* in_sizes, int n_in,
                              void* d_out, int out_size, void* d_ws, size_t ws_size,
                              hipStream_t stream){
  (void)in_sizes; (void)n_in; (void)out_size; (void)ws_size;
  const float* enc  = (const float*)d_in[0];
  const float* spec = (const float*)d_in[1];
  const float* embw = (const float*)d_in[2];
  const float* outw = (const float*)d_in[3];
  const float* outb = (const float*)d_in[4];
  const float* gumb = (const float*)d_in[5];
  const float* saqw = (const float*)d_in[6];
  const float* saqb = (const float*)d_in[7];
  const float* saow = (const float*)d_in[8];
  const float* saob = (const float*)d_in[9];
  const float* caqw = (const float*)d_in[10];
  const float* caqb = (const float*)d_in[11];
  const float* caow = (const float*)d_in[12];
  const float* caob = (const float*)d_in[13];
  const float* l1g  = (const float*)d_in[14];
  const float* l1b  = (const float*)d_in[15];
  const float* l2g  = (const float*)d_in[16];
  const float* l2b  = (const float*)d_in[17];
  const float* l3g  = (const float*)d_in[18];
  const float* l3b  = (const float*)d_in[19];
  const float* w1   = (const float*)d_in[20];
  const float* b1   = (const float*)d_in[21];
  const float* w2   = (const float*)d_in[22];
  const float* b2   = (const float*)d_in[23];

  float* dout = (float*)d_out;
  float* dseq = dout;
  float* ddistbase = dout + (size_t)BB*(TT+1)*VV;

  float* ws = (float*)d_ws;
  float* x      = ws; ws += BB*EE;
  float* y      = ws; ws += BB*EE;
  float* q      = ws; ws += BB*EE;
  float* H      = ws; ws += BB*FFD;
  float* logits = ws; ws += BB*VV;
  float* venc   = ws; ws += LL*BB*EE;
  float* cac    = ws; ws += LL*BB*EE;
  float* kcache = ws; ws += (size_t)LL*BB*NHD*TT*HDD;
  float* vcache = ws; ws += (size_t)LL*BB*NHD*TT*HDD;

  k_init<<<1088, 256, 0, stream>>>(spec, dseq, x);
  k_penc<<<32, 256, 0, stream>>>(enc, caqw, caqb, venc);
  k_pca<<<32, 256, 0, stream>>>(venc, caow, caob, cac);

  for (int step = 0; step < TT; ++step){
    const int tpos = step, tlen = step + 1;
    for (int l = 0; l < LL; ++l){
      const int use_ln = (l > 0);
      const float* lg = l3g + (use_ln ? (l-1)*EE : 0);
      const float* lb = l3b + (use_ln ? (l-1)*EE : 0);
      float* kcl = kcache + (size_t)l*BB*NHD*TT*HDD;
      float* vcl = vcache + (size_t)l*BB*NHD*TT*HDD;
      k_qkv<<<24, 256, 0, stream>>>(x, y, lg, lb, use_ln,
          saqw + (size_t)l*3*EE*EE, saqb + l*3*EE, q, kcl, vcl, tpos);
      k_attnfused<<<32, 256, 0, stream>>>(x, y, lg, lb, use_ln, q, kcl, vcl, tlen,
          saow + (size_t)l*EE*EE, saob + l*EE,
          l1g + l*EE, l1b + l*EE, l2g + l*EE, l2b + l*EE,
          cac + (size_t)l*BB*EE, b2 + l*EE, x, y);
      k_ffn1<<<32, 256, 0, stream>>>(x, w1 + (size_t)l*FFD*EE, b1 + l*FFD, H);
      k_ffn2<<<32, 256, 0, stream>>>(H, w2 + (size_t)l*EE*FFD, y);
    }
    k_logits<<<128, 256, 0, stream>>>(y, l3g + 3*EE, l3b + 3*EE, outw, outb, logits);
    k_softmax<<<32, 256, 0, stream>>>(logits, gumb + (size_t)step*BB*VV, dseq,
        ddistbase + (size_t)step*BB*VV, x, step);
    k_embed<<<128, 256, 0, stream>>>(embw, dseq, step, x);
  }
}

// Round 2
// 4792.924 us; speedup vs baseline: 2.2324x; 2.2324x over previous
//
#include <hip/hip_runtime.h>
#include <math.h>

#define BB 32
#define EE 512
#define VV 8192
#define TT 16
#define LL 4
#define FFD 2048
#define NHD 8
#define HDD 64
#define LDP 520   // padded LDS pitch (bf16 elems): 1040B rows -> 2-way-free b128 reads
#define SCALE_EMB 22.627416997969522f

typedef __attribute__((ext_vector_type(8))) short bf16x8;   // 8 bf16 in 4 VGPRs
typedef __attribute__((ext_vector_type(4))) float f32x4;

__device__ __forceinline__ f32x4 mfma16(bf16x8 a, bf16x8 b, f32x4 c){
  return __builtin_amdgcn_mfma_f32_16x16x32_bf16(a, b, c, 0, 0, 0);
}

// ---------------- helpers ----------------
__device__ __forceinline__ float wave_sum(float v){
  for (int o = 32; o; o >>= 1) v += __shfl_down(v, o);
  return __shfl(v, 0);
}
__device__ __forceinline__ float wave_max(float v){
  for (int o = 32; o; o >>= 1) v = fmaxf(v, __shfl_down(v, o));
  return __shfl(v, 0);
}
__device__ __forceinline__ unsigned short f_to_bf(float f){
  unsigned u = __float_as_uint(f);
  unsigned r = (u + 0x7fffu + ((u >> 16) & 1u)) >> 16;
  return (unsigned short)r;
}
__device__ __forceinline__ float2 bf2_to_f2(const unsigned short* p){
  unsigned u = *(const unsigned*)p;
  float2 r;
  r.x = __uint_as_float(u << 16);
  r.y = __uint_as_float(u & 0xffff0000u);
  return r;
}

// fp32 VALU GEMM core (kept for the one-off prologue kernels k_penc/k_pca)
__device__ __forceinline__ void gemm_chunk(const float* __restrict__ wrow0, int ldw,
    const unsigned short* xs, float* wt, float acc[4][2]){
  const int t = threadIdx.x, fg = t & 15, bg = t >> 4;
  #pragma unroll 1
  for (int c = 0; c < 8; ++c){
    const int k0 = c*64;
    __syncthreads();
    {
      int i = t*4;
      #pragma unroll
      for (int p = 0; p < 4; ++p, i += 1024){
        const int fr = i >> 6, kk = i & 63;
        float4 v = *(const float4*)(wrow0 + (size_t)fr*ldw + k0 + kk);
        wt[(kk+0)*68 + fr] = v.x;
        wt[(kk+1)*68 + fr] = v.y;
        wt[(kk+2)*68 + fr] = v.z;
        wt[(kk+3)*68 + fr] = v.w;
      }
    }
    __syncthreads();
    const unsigned short* xr0 = xs + (bg*2)*EE + k0;
    const unsigned short* xr1 = xr0 + EE;
    #pragma unroll 8
    for (int k = 0; k < 64; k += 2){
      float w0[4], w1[4];
      *(float4*)w0 = *(const float4*)(wt + (k+0)*68 + fg*4);
      *(float4*)w1 = *(const float4*)(wt + (k+1)*68 + fg*4);
      float2 xv0 = bf2_to_f2(xr0 + k);
      float2 xv1 = bf2_to_f2(xr1 + k);
      #pragma unroll
      for (int i = 0; i < 4; ++i){
        acc[i][0] += w0[i]*xv0.x + w1[i]*xv0.y;
        acc[i][1] += w0[i]*xv1.x + w1[i]*xv1.y;
      }
    }
  }
}

// Stage [B,E] activations into padded-LDS bf16, optional pending LN3 from ybuf.
// If xlnout != null (block 0, use_ln=1) also materialize the LN'd fp32 rows.
__device__ __forceinline__ void stage_x_p(unsigned short* xs,
    const float* __restrict__ xraw, const float* __restrict__ ybuf,
    const float* __restrict__ g, const float* __restrict__ bt, int use_ln,
    float* __restrict__ xlnout){
  if (!use_ln){
    for (int i = threadIdx.x; i < BB*EE; i += 256){
      int r = i >> 9, c = i & 511;
      xs[r*LDP + c] = f_to_bf(xraw[i]);
    }
  } else {
    const int lane = threadIdx.x & 63, wv = threadIdx.x >> 6;
    for (int r = wv*8; r < wv*8 + 8; ++r){
      float vals[8]; float s = 0.f, s2 = 0.f;
      #pragma unroll
      for (int j = 0; j < 8; ++j){
        float v = ybuf[r*EE + lane + j*64];
        vals[j] = v; s += v; s2 += v*v;
      }
      s = wave_sum(s); s2 = wave_sum(s2);
      float m = s * (1.f/EE);
      float inv = rsqrtf(s2*(1.f/EE) - m*m + 1e-5f);
      #pragma unroll
      for (int j = 0; j < 8; ++j){
        int c = lane + j*64;
        float v = (vals[j]-m)*inv*g[c] + bt[c];
        xs[r*LDP + c] = f_to_bf(v);
        if (xlnout) xlnout[r*EE + c] = v;
      }
    }
  }
  __syncthreads();
}

// ---------------- prologue kernels ----------------

__global__ __launch_bounds__(256) void k_init(const float* __restrict__ special,
    float* __restrict__ dseq, float* __restrict__ x){
  int idx = blockIdx.x*256 + threadIdx.x;
  if (idx < BB*VV){
    int b = idx >> 13, v = idx & (VV-1);
    dseq[(size_t)b*((TT+1)*VV) + (size_t)TT*VV + v] = (v == 0) ? 1.f : 0.f;
  } else {
    int i = idx - BB*VV;
    x[i] = special[i & (EE-1)];
  }
}

__global__ __launch_bounds__(256) void k_penc(const float* __restrict__ enc,
    const float* __restrict__ w, const float* __restrict__ bias, float* __restrict__ venc){
  __shared__ unsigned short xs[BB*EE];
  __shared__ float wt[64*68];
  const int l = blockIdx.x >> 3, et = blockIdx.x & 7;
  for (int i = threadIdx.x; i < BB*EE; i += 256) xs[i] = f_to_bf(enc[i]);
  const int t = threadIdx.x, fg = t & 15, bg = t >> 4;
  const int f0 = et*64;
  const float* wl = w + (size_t)l*3*EE*EE + (size_t)(2*EE + f0)*EE;
  const float* bl = bias + l*3*EE + 2*EE + f0;
  float acc[4][2];
  #pragma unroll
  for (int i = 0; i < 4; ++i){ float bv = bl[fg*4+i]; acc[i][0] = bv; acc[i][1] = bv; }
  gemm_chunk(wl, EE, xs, wt, acc);
  #pragma unroll
  for (int i = 0; i < 4; ++i)
    #pragma unroll
    for (int j = 0; j < 2; ++j)
      venc[(size_t)l*BB*EE + (bg*2+j)*EE + f0 + fg*4 + i] = acc[i][j];
}

__global__ __launch_bounds__(256) void k_pca(const float* __restrict__ venc,
    const float* __restrict__ w, const float* __restrict__ bias, float* __restrict__ cac){
  __shared__ unsigned short xs[BB*EE];
  __shared__ float wt[64*68];
  const int l = blockIdx.x >> 3, et = blockIdx.x & 7;
  const float* vin = venc + (size_t)l*BB*EE;
  for (int i = threadIdx.x; i < BB*EE; i += 256) xs[i] = f_to_bf(vin[i]);
  const int t = threadIdx.x, fg = t & 15, bg = t >> 4;
  const int f0 = et*64;
  const float* wl = w + (size_t)l*EE*EE + (size_t)f0*EE;
  const float* bl = bias + l*EE + f0;
  float acc[4][2];
  #pragma unroll
  for (int i = 0; i < 4; ++i){ float bv = bl[fg*4+i]; acc[i][0] = bv; acc[i][1] = bv; }
  gemm_chunk(wl, EE, xs, wt, acc);
  #pragma unroll
  for (int i = 0; i < 4; ++i)
    #pragma unroll
    for (int j = 0; j < 2; ++j)
      cac[(size_t)l*BB*EE + (bg*2+j)*EE + f0 + fg*4 + i] = acc[i][j];
}

// fp32 -> bf16 weight conversion (vectorized by 4)
__global__ __launch_bounds__(256) void k_cvt(const float* __restrict__ s,
    unsigned short* __restrict__ d, int n4){
  int i = blockIdx.x*256 + threadIdx.x;
  if (i < n4){
    float4 v = ((const float4*)s)[i];
    ushort4 o;
    o.x = f_to_bf(v.x); o.y = f_to_bf(v.y); o.z = f_to_bf(v.z); o.w = f_to_bf(v.w);
    ((ushort4*)d)[i] = o;
  }
}

// embT[e][v] = bf16(emb[v][e]) — transposed copy so both embed-GEMM operands are contiguous
__global__ __launch_bounds__(256) void k_embT(const float* __restrict__ emb,
    unsigned short* __restrict__ eT){
  __shared__ unsigned short tl[64][68];
  const int vt = blockIdx.x >> 3, et = blockIdx.x & 7;
  const int v0 = vt*64, e0 = et*64;
  for (int i = threadIdx.x; i < 64*64; i += 256){
    int vv = i >> 6, ee = i & 63;
    tl[vv][ee] = f_to_bf(emb[(size_t)(v0+vv)*EE + e0 + ee]);
  }
  __syncthreads();
  for (int i = threadIdx.x; i < 64*64; i += 256){
    int ee = i >> 6, vv = i & 63;
    eT[(size_t)(e0+ee)*VV + v0 + vv] = tl[vv][ee];
  }
}

// ---------------- per-step kernels ----------------

// qkv projection: MFMA over bf16 weights (A direct from global), x staged+LN'd in LDS.
// block = 64 f rows (4 waves x 16f), all 32 b. grid 24.
__global__ __launch_bounds__(256) void k_qkv_m(
    const float* __restrict__ x, const float* __restrict__ ybuf,
    const float* __restrict__ lng, const float* __restrict__ lnb, int use_ln,
    const unsigned short* __restrict__ Wb, const float* __restrict__ bias,
    float* __restrict__ qbuf, float* __restrict__ kc, float* __restrict__ vc,
    int tpos, float* __restrict__ xln){
  __shared__ unsigned short xs[BB*LDP];
  float* xlo = (use_ln && blockIdx.x == 0) ? xln : nullptr;
  stage_x_p(xs, x, ybuf, lng, lnb, use_ln, xlo);
  const int t = threadIdx.x, w = t >> 6, l = t & 63;
  const int lm = l & 15, kg = l >> 4;
  const int f0w = blockIdx.x*64 + w*16;
  const unsigned short* ar = Wb + (size_t)(f0w + lm)*EE + kg*8;
  const unsigned short* b0r = xs + lm*LDP + kg*8;
  const unsigned short* b1r = xs + (lm+16)*LDP + kg*8;
  f32x4 acc0 = {0.f,0.f,0.f,0.f}, acc1 = {0.f,0.f,0.f,0.f};
  #pragma unroll 4
  for (int ks = 0; ks < 16; ++ks){
    bf16x8 a  = *reinterpret_cast<const bf16x8*>(ar + ks*32);
    bf16x8 b0 = *reinterpret_cast<const bf16x8*>(b0r + ks*32);
    bf16x8 b1 = *reinterpret_cast<const bf16x8*>(b1r + ks*32);
    acc0 = mfma16(a, b0, acc0);
    acc1 = mfma16(a, b1, acc1);
  }
  #pragma unroll
  for (int r = 0; r < 4; ++r){
    const int f = f0w + kg*4 + r;
    const float bv = bias[f];
    float v0 = acc0[r] + bv, v1 = acc1[r] + bv;
    if (f < EE){
      qbuf[lm*EE + f] = v0;
      qbuf[(lm+16)*EE + f] = v1;
    } else if (f < 2*EE){
      int ff = f - EE, h = ff >> 6, d = ff & 63;
      kc[((size_t)(lm*NHD + h)*TT + tpos)*HDD + d] = v0;
      kc[((size_t)((lm+16)*NHD + h)*TT + tpos)*HDD + d] = v1;
    } else {
      int ff = f - 2*EE, h = ff >> 6, d = ff & 63;
      vc[((size_t)(lm*NHD + h)*TT + tpos)*HDD + d] = v0;
      vc[((size_t)((lm+16)*NHD + h)*TT + tpos)*HDD + d] = v1;
    }
  }
}

// attention core per batch row: softmax(q.K/8) @ V -> obf bf16 [32][512]
__global__ __launch_bounds__(256) void k_attn(
    const float* __restrict__ qbuf, const float* __restrict__ kc,
    const float* __restrict__ vc, int tlen, unsigned short* __restrict__ obf){
  const int b = blockIdx.x, t = threadIdx.x, lane = t & 63, wv = t >> 6;
  __shared__ float att[NHD*16];
  #pragma unroll
  for (int hh = 0; hh < 2; ++hh){
    const int h = wv*2 + hh;
    const float* kh = kc + (size_t)(b*NHD + h)*TT*HDD;
    const float* vh = vc + (size_t)(b*NHD + h)*TT*HDD;
    const float* qh = qbuf + b*EE + h*HDD;
    float sc = -1e30f;
    if (lane < tlen){
      float a = 0.f;
      for (int d = 0; d < HDD; d += 4){
        float4 qv = *(const float4*)(qh + d);
        float4 kv = *(const float4*)(kh + lane*HDD + d);
        a += qv.x*kv.x + qv.y*kv.y + qv.z*kv.z + qv.w*kv.w;
      }
      sc = a*0.125f;
    }
    float m = wave_max(sc);
    float e = (lane < tlen) ? __expf(sc - m) : 0.f;
    float s = wave_sum(e);
    if (lane < 16) att[h*16 + lane] = e / s;
    float o = 0.f;
    for (int j = 0; j < tlen; ++j) o += att[h*16 + j] * vh[j*HDD + lane];
    obf[b*EE + h*HDD + lane] = f_to_bf(o);
  }
}

// out-projection GEMM + bias + residual -> o2 fp32 (LN1 pending). grid 8.
__global__ __launch_bounds__(256) void k_outp(
    const unsigned short* __restrict__ obf, const unsigned short* __restrict__ Wb,
    const float* __restrict__ ob, const float* __restrict__ resid, float* __restrict__ o2){
  const int t = threadIdx.x, w = t >> 6, l = t & 63;
  const int lm = l & 15, kg = l >> 4;
  const int f0w = blockIdx.x*64 + w*16;
  const unsigned short* ar = Wb + (size_t)(f0w + lm)*EE + kg*8;
  const unsigned short* b0r = obf + lm*EE + kg*8;
  const unsigned short* b1r = obf + (lm+16)*EE + kg*8;
  f32x4 acc0 = {0.f,0.f,0.f,0.f}, acc1 = {0.f,0.f,0.f,0.f};
  #pragma unroll 4
  for (int ks = 0; ks < 16; ++ks){
    bf16x8 a  = *reinterpret_cast<const bf16x8*>(ar + ks*32);
    bf16x8 b0 = *reinterpret_cast<const bf16x8*>(b0r + ks*32);
    bf16x8 b1 = *reinterpret_cast<const bf16x8*>(b1r + ks*32);
    acc0 = mfma16(a, b0, acc0);
    acc1 = mfma16(a, b1, acc1);
  }
  #pragma unroll
  for (int r = 0; r < 4; ++r){
    const int f = f0w + kg*4 + r;
    const float bv = ob[f];
    o2[lm*EE + f]      = acc0[r] + bv + resid[lm*EE + f];
    o2[(lm+16)*EE + f] = acc1[r] + bv + resid[(lm+16)*EE + f];
  }
}

// ffn1: prologue per-row LN1 -> +cac -> LN2 (staged to LDS bf16; block0 also writes
// ybuf = x2 + b2 for ffn2's k-split atomics), then MFMA gelu(x2 @ w1.T + b1). grid 32.
__global__ __launch_bounds__(256) void k_ffn1_m(
    const float* __restrict__ o2, const float* __restrict__ cac,
    const float* __restrict__ g1, const float* __restrict__ b1g,
    const float* __restrict__ g2, const float* __restrict__ b2g,
    const float* __restrict__ b2bias,
    const unsigned short* __restrict__ Wb, const float* __restrict__ bias,
    unsigned short* __restrict__ Hb, float* __restrict__ ybuf){
  __shared__ unsigned short xs[BB*LDP];
  {
    float* yi = (blockIdx.x == 0) ? ybuf : nullptr;
    const int lane = threadIdx.x & 63, wv = threadIdx.x >> 6;
    for (int r = wv*8; r < wv*8 + 8; ++r){
      float vals[8]; float s = 0.f, s2 = 0.f;
      #pragma unroll
      for (int j = 0; j < 8; ++j){
        float v = o2[r*EE + lane + j*64];
        vals[j] = v; s += v; s2 += v*v;
      }
      s = wave_sum(s); s2 = wave_sum(s2);
      float m = s*(1.f/EE), inv = rsqrtf(s2*(1.f/EE) - m*m + 1e-5f);
      float nv[8]; float u = 0.f, u2 = 0.f;
      #pragma unroll
      for (int j = 0; j < 8; ++j){
        int c = lane + j*64;
        float v = (vals[j]-m)*inv*g1[c] + b1g[c] + cac[r*EE + c];
        nv[j] = v; u += v; u2 += v*v;
      }
      u = wave_sum(u); u2 = wave_sum(u2);
      float m2 = u*(1.f/EE), inv2 = rsqrtf(u2*(1.f/EE) - m2*m2 + 1e-5f);
      #pragma unroll
      for (int j = 0; j < 8; ++j){
        int c = lane + j*64;
        float v = (nv[j]-m2)*inv2*g2[c] + b2g[c];
        xs[r*LDP + c] = f_to_bf(v);
        if (yi) yi[r*EE + c] = v + b2bias[c];
      }
    }
    __syncthreads();
  }
  const int t = threadIdx.x, w = t >> 6, l = t & 63;
  const int lm = l & 15, kg = l >> 4;
  const int f0w = blockIdx.x*64 + w*16;
  const unsigned short* ar = Wb + (size_t)(f0w + lm)*EE + kg*8;
  const unsigned short* b0r = xs + lm*LDP + kg*8;
  const unsigned short* b1r = xs + (lm+16)*LDP + kg*8;
  f32x4 acc0 = {0.f,0.f,0.f,0.f}, acc1 = {0.f,0.f,0.f,0.f};
  #pragma unroll 4
  for (int ks = 0; ks < 16; ++ks){
    bf16x8 a  = *reinterpret_cast<const bf16x8*>(ar + ks*32);
    bf16x8 b0 = *reinterpret_cast<const bf16x8*>(b0r + ks*32);
    bf16x8 b1 = *reinterpret_cast<const bf16x8*>(b1r + ks*32);
    acc0 = mfma16(a, b0, acc0);
    acc1 = mfma16(a, b1, acc1);
  }
  #pragma unroll
  for (int r = 0; r < 4; ++r){
    const int f = f0w + kg*4 + r;
    const float bv = bias[f];
    float v0 = acc0[r] + bv, v1 = acc1[r] + bv;
    v0 = 0.5f*v0*(1.f + erff(v0*0.70710678118654752f));
    v1 = 0.5f*v1*(1.f + erff(v1*0.70710678118654752f));
    Hb[lm*FFD + f] = f_to_bf(v0);
    Hb[(lm+16)*FFD + f] = f_to_bf(v1);
  }
}

// ffn2: y += H @ w2.T  (k-split x4, atomics; H bf16 direct from global). grid 32.
__global__ __launch_bounds__(256) void k_ffn2_m(
    const unsigned short* __restrict__ Hb, const unsigned short* __restrict__ Wb,
    float* __restrict__ ybuf){
  const int t = threadIdx.x, w = t >> 6, l = t & 63;
  const int lm = l & 15, kg = l >> 4;
  const int f0w = (blockIdx.x & 7)*64 + w*16;
  const int k0 = (blockIdx.x >> 3)*512;
  const unsigned short* ar = Wb + (size_t)(f0w + lm)*FFD + k0 + kg*8;
  const unsigned short* b0r = Hb + lm*FFD + k0 + kg*8;
  const unsigned short* b1r = Hb + (lm+16)*FFD + k0 + kg*8;
  f32x4 acc0 = {0.f,0.f,0.f,0.f}, acc1 = {0.f,0.f,0.f,0.f};
  #pragma unroll 4
  for (int ks = 0; ks < 16; ++ks){
    bf16x8 a  = *reinterpret_cast<const bf16x8*>(ar + ks*32);
    bf16x8 b0 = *reinterpret_cast<const bf16x8*>(b0r + ks*32);
    bf16x8 b1 = *reinterpret_cast<const bf16x8*>(b1r + ks*32);
    acc0 = mfma16(a, b0, acc0);
    acc1 = mfma16(a, b1, acc1);
  }
  #pragma unroll
  for (int r = 0; r < 4; ++r){
    const int f = f0w + kg*4 + r;
    atomicAdd(&ybuf[lm*EE + f], acc0[r]);
    atomicAdd(&ybuf[(lm+16)*EE + f], acc1[r]);
  }
}

// logits = LN3(y) @ out_w.T + out_b. grid 128.
__global__ __launch_bounds__(256) void k_logits_m(
    const float* __restrict__ ybuf, const float* __restrict__ lng, const float* __restrict__ lnb,
    const unsigned short* __restrict__ Wb, const float* __restrict__ bias,
    float* __restrict__ logits){
  __shared__ unsigned short xs[BB*LDP];
  stage_x_p(xs, nullptr, ybuf, lng, lnb, 1, nullptr);
  const int t = threadIdx.x, w = t >> 6, l = t & 63;
  const int lm = l & 15, kg = l >> 4;
  const int f0w = blockIdx.x*64 + w*16;
  const unsigned short* ar = Wb + (size_t)(f0w + lm)*EE + kg*8;
  const unsigned short* b0r = xs + lm*LDP + kg*8;
  const unsigned short* b1r = xs + (lm+16)*LDP + kg*8;
  f32x4 acc0 = {0.f,0.f,0.f,0.f}, acc1 = {0.f,0.f,0.f,0.f};
  #pragma unroll 4
  for (int ks = 0; ks < 16; ++ks){
    bf16x8 a  = *reinterpret_cast<const bf16x8*>(ar + ks*32);
    bf16x8 b0 = *reinterpret_cast<const bf16x8*>(b0r + ks*32);
    bf16x8 b1 = *reinterpret_cast<const bf16x8*>(b1r + ks*32);
    acc0 = mfma16(a, b0, acc0);
    acc1 = mfma16(a, b1, acc1);
  }
  #pragma unroll
  for (int r = 0; r < 4; ++r){
    const int f = f0w + kg*4 + r;
    const float bv = bias[f];
    logits[lm*VV + f]      = acc0[r] + bv;
    logits[(lm+16)*VV + f] = acc1[r] + bv;
  }
}

// dual softmax; writes distrib + gumbel sample (fp32 to d_out, bf16 sample to ws), zeroes x
__global__ __launch_bounds__(256) void k_softmax(const float* __restrict__ logits,
    const float* __restrict__ gum, float* __restrict__ dseq, float* __restrict__ ddist,
    unsigned short* __restrict__ sbf, float* __restrict__ x, int step){
  const int b = blockIdx.x, t = threadIdx.x, lane = t & 63, wv = t >> 6;
  __shared__ float red[8];
  const float* lr = logits + (size_t)b*VV;
  const float* gr = gum + (size_t)b*VV;
  float m1 = -1e30f, m2 = -1e30f;
  for (int i = t; i < VV; i += 256){
    float l = lr[i];
    m1 = fmaxf(m1, l);
    m2 = fmaxf(m2, l + gr[i]);
  }
  for (int o = 32; o; o >>= 1){ m1 = fmaxf(m1, __shfl_down(m1,o)); m2 = fmaxf(m2, __shfl_down(m2,o)); }
  if (lane == 0){ red[wv] = m1; red[4+wv] = m2; }
  __syncthreads();
  m1 = fmaxf(fmaxf(red[0],red[1]), fmaxf(red[2],red[3]));
  m2 = fmaxf(fmaxf(red[4],red[5]), fmaxf(red[6],red[7]));
  __syncthreads();
  float s1 = 0.f, s2 = 0.f;
  for (int i = t; i < VV; i += 256){
    float l = lr[i];
    s1 += __expf(l - m1);
    s2 += __expf(l + gr[i] - m2);
  }
  for (int o = 32; o; o >>= 1){ s1 += __shfl_down(s1,o); s2 += __shfl_down(s2,o); }
  if (lane == 0){ red[wv] = s1; red[4+wv] = s2; }
  __syncthreads();
  s1 = red[0]+red[1]+red[2]+red[3];
  s2 = red[4]+red[5]+red[6]+red[7];
  float r1 = 1.f/s1, r2 = 1.f/s2;
  float* dq = dseq + (size_t)b*((TT+1)*VV) + (size_t)step*VV;
  float* dd = ddist + (size_t)b*VV;
  for (int i = t; i < VV; i += 256){
    float l = lr[i];
    dd[i] = __expf(l - m1)*r1;
    float qv = __expf(l + gr[i] - m2)*r2;
    dq[i] = qv;
    sbf[(size_t)b*VV + i] = f_to_bf(qv);
  }
  for (int i = t; i < EE; i += 256) x[b*EE + i] = 0.f;
}

// x += (sample @ emb) * sqrt(E): MFMA over embT (A) and sbf (B), k-split x8, atomics. grid 64.
__global__ __launch_bounds__(256) void k_embed_m(
    const unsigned short* __restrict__ eT, const unsigned short* __restrict__ sbf,
    float* __restrict__ x){
  const int t = threadIdx.x, w = t >> 6, l = t & 63;
  const int lm = l & 15, kg = l >> 4;
  const int e0w = (blockIdx.x & 7)*64 + w*16;
  const int v0 = (blockIdx.x >> 3)*1024;
  const unsigned short* ar  = eT + (size_t)(e0w + lm)*VV + v0 + kg*8;
  const unsigned short* b0r = sbf + (size_t)lm*VV + v0 + kg*8;
  const unsigned short* b1r = sbf + (size_t)(lm+16)*VV + v0 + kg*8;
  f32x4 acc0 = {0.f,0.f,0.f,0.f}, acc1 = {0.f,0.f,0.f,0.f};
  #pragma unroll 8
  for (int ks = 0; ks < 32; ++ks){
    bf16x8 a  = *reinterpret_cast<const bf16x8*>(ar + ks*32);
    bf16x8 b0 = *reinterpret_cast<const bf16x8*>(b0r + ks*32);
    bf16x8 b1 = *reinterpret_cast<const bf16x8*>(b1r + ks*32);
    acc0 = mfma16(a, b0, acc0);
    acc1 = mfma16(a, b1, acc1);
  }
  #pragma unroll
  for (int r = 0; r < 4; ++r){
    const int e = e0w + kg*4 + r;
    atomicAdd(&x[lm*EE + e], acc0[r]*SCALE_EMB);
    atomicAdd(&x[(lm+16)*EE + e], acc1[r]*SCALE_EMB);
  }
}

// ---------------- host ----------------
extern "C" void kernel_launch(void* const* d_in, const int* in_sizes, int n_in,
                              void* d_out, int out_size, void* d_ws, size_t ws_size,
                              hipStream_t stream){
  (void)in_sizes; (void)n_in; (void)out_size; (void)ws_size;
  const float* enc  = (const float*)d_in[0];
  const float* spec = (const float*)d_in[1];
  const float* embw = (const float*)d_in[2];
  const float* outw = (const float*)d_in[3];
  const float* outb = (const float*)d_in[4];
  const float* gumb = (const float*)d_in[5];
  const float* saqw = (const float*)d_in[6];
  const float* saqb = (const float*)d_in[7];
  const float* saow = (const float*)d_in[8];
  const float* saob = (const float*)d_in[9];
  const float* caqw = (const float*)d_in[10];
  const float* caqb = (const float*)d_in[11];
  const float* caow = (const float*)d_in[12];
  const float* caob = (const float*)d_in[13];
  const float* l1g  = (const float*)d_in[14];
  const float* l1b  = (const float*)d_in[15];
  const float* l2g  = (const float*)d_in[16];
  const float* l2b  = (const float*)d_in[17];
  const float* l3g  = (const float*)d_in[18];
  const float* l3b  = (const float*)d_in[19];
  const float* w1   = (const float*)d_in[20];
  const float* b1   = (const float*)d_in[21];
  const float* w2   = (const float*)d_in[22];
  const float* b2   = (const float*)d_in[23];

  float* dout = (float*)d_out;
  float* dseq = dout;
  float* ddistbase = dout + (size_t)BB*(TT+1)*VV;

  unsigned char* p = (unsigned char*)d_ws;
  auto alloc = [&](size_t bytes) -> void* {
    void* r = (void*)p; p += (bytes + 255) & ~(size_t)255; return r;
  };
  float* x      = (float*)alloc(BB*EE*4);
  float* y      = (float*)alloc(BB*EE*4);
  float* q      = (float*)alloc(BB*EE*4);
  float* xln    = (float*)alloc(BB*EE*4);
  float* o2     = (float*)alloc(BB*EE*4);
  float* logits = (float*)alloc((size_t)BB*VV*4);
  float* venc   = (float*)alloc((size_t)LL*BB*EE*4);
  float* cac    = (float*)alloc((size_t)LL*BB*EE*4);
  float* kcache = (float*)alloc((size_t)LL*BB*EE*TT*4);
  float* vcache = (float*)alloc((size_t)LL*BB*EE*TT*4);
  unsigned short* obf   = (unsigned short*)alloc(BB*EE*2);
  unsigned short* Hb    = (unsigned short*)alloc(BB*FFD*2);
  unsigned short* sbf   = (unsigned short*)alloc((size_t)BB*VV*2);
  unsigned short* wqkvb = (unsigned short*)alloc((size_t)LL*3*EE*EE*2);
  unsigned short* owb   = (unsigned short*)alloc((size_t)LL*EE*EE*2);
  unsigned short* w1b   = (unsigned short*)alloc((size_t)LL*FFD*EE*2);
  unsigned short* w2b   = (unsigned short*)alloc((size_t)LL*FFD*EE*2);
  unsigned short* outwb = (unsigned short*)alloc((size_t)VV*EE*2);
  unsigned short* eTb   = (unsigned short*)alloc((size_t)EE*VV*2);

  // prologue: init, cross-attn constants, bf16 weight conversions
  k_init<<<1088, 256, 0, stream>>>(spec, dseq, x);
  k_penc<<<32, 256, 0, stream>>>(enc, caqw, caqb, venc);
  k_pca<<<32, 256, 0, stream>>>(venc, caow, caob, cac);
  k_cvt<<<(LL*3*EE*EE/4 + 255)/256, 256, 0, stream>>>(saqw, wqkvb, LL*3*EE*EE/4);
  k_cvt<<<(LL*EE*EE/4 + 255)/256, 256, 0, stream>>>(saow, owb, LL*EE*EE/4);
  k_cvt<<<(LL*FFD*EE/4 + 255)/256, 256, 0, stream>>>(w1, w1b, LL*FFD*EE/4);
  k_cvt<<<(LL*FFD*EE/4 + 255)/256, 256, 0, stream>>>(w2, w2b, LL*FFD*EE/4);
  k_cvt<<<(VV*EE/4 + 255)/256, 256, 0, stream>>>(outw, outwb, VV*EE/4);
  k_embT<<<1024, 256, 0, stream>>>(embw, eTb);

  for (int step = 0; step < TT; ++step){
    const int tpos = step, tlen = step + 1;
    for (int l = 0; l < LL; ++l){
      const int use_ln = (l > 0);
      const float* lg = l3g + (use_ln ? (l-1)*EE : 0);
      const float* lb = l3b + (use_ln ? (l-1)*EE : 0);
      float* kcl = kcache + (size_t)l*BB*EE*TT;
      float* vcl = vcache + (size_t)l*BB*EE*TT;
      const float* resid = use_ln ? xln : x;
      k_qkv_m<<<24, 256, 0, stream>>>(x, y, lg, lb, use_ln,
          wqkvb + (size_t)l*3*EE*EE, saqb + l*3*EE, q, kcl, vcl, tpos, xln);
      k_attn<<<32, 256, 0, stream>>>(q, kcl, vcl, tlen, obf);
      k_outp<<<8, 256, 0, stream>>>(obf, owb + (size_t)l*EE*EE, saob + l*EE, resid, o2);
      k_ffn1_m<<<32, 256, 0, stream>>>(o2, cac + (size_t)l*BB*EE,
          l1g + l*EE, l1b + l*EE, l2g + l*EE, l2b + l*EE, b2 + l*EE,
          w1b + (size_t)l*FFD*EE, b1 + l*FFD, Hb, y);
      k_ffn2_m<<<32, 256, 0, stream>>>(Hb, w2b + (size_t)l*EE*FFD, y);
    }
    k_logits_m<<<128, 256, 0, stream>>>(y, l3g + 3*EE, l3b + 3*EE, outwb, outb, logits);
    k_softmax<<<32, 256, 0, stream>>>(logits, gumb + (size_t)step*BB*VV, dseq,
        ddistbase + (size_t)step*BB*VV, sbf, x, step);
    k_embed_m<<<64, 256, 0, stream>>>(eTb, sbf, x);
  }
}